// Round 1
// baseline (500.844 us; speedup 1.0000x reference)
//
#include <hip/hip_runtime.h>
#include <hip/hip_bf16.h>
#include <stdint.h>
#include <stddef.h>

typedef __bf16 bf16x8 __attribute__((ext_vector_type(8)));
typedef float f32x4 __attribute__((ext_vector_type(4)));
typedef __hip_bfloat16 bf16_t;

#define BM 128
#define BN 128
#define BK 64
#define THREADS 256

// async global->LDS, 16B per lane. LDS dest must be wave-uniform-base + lane*16.
__device__ __forceinline__ void stage16(const void* g, void* l) {
  __builtin_amdgcn_global_load_lds(
      (const __attribute__((address_space(1))) uint32_t*)g,
      (__attribute__((address_space(3))) uint32_t*)l, 16, 0, 0);
}

__device__ __forceinline__ unsigned pk2(float x, float y) {
  bf16_t a = __float2bfloat16(x);
  bf16_t b = __float2bfloat16(y);
  unsigned short ua = *(unsigned short*)&a;
  unsigned short ub = *(unsigned short*)&b;
  return (unsigned)ua | ((unsigned)ub << 16);
}

// C = A @ Bt^T.  A: [M,K] row-major bf16.  Bt: [N,K] row-major bf16.
// OUT_MODE 0: C bf16 row-major [M,N] (ld=N)
// OUT_MODE 1: C bf16 TRANSPOSED [N,M] (ld=M)  (for support^T buffers)
// OUT_MODE 2: C f32 row-major [M,N]
// sA/sB/sC: per-batch element strides (blockIdx.z = batch).
template <int OUT_MODE, bool RELU>
__global__ void gemm_bt(const bf16_t* __restrict__ A, const bf16_t* __restrict__ Bt,
                        void* __restrict__ Cv, int M, int N, int K,
                        long sA, long sB, long sC) {
  __shared__ __align__(16) char lds[(BM + BN) * BK * 2];  // 32 KB
  char* ldsA = lds;
  char* ldsB = lds + BM * BK * 2;

  const int t = threadIdx.x;
  const int lane = t & 63;
  const int w = t >> 6;
  const int wm = w >> 1, wn = w & 1;          // 2x2 wave grid, each wave 64x64
  const int quad = lane >> 4, l15 = lane & 15;
  const int m0 = blockIdx.x * BM;
  const int n0 = blockIdx.y * BN;
  const int b = blockIdx.z;

  const bf16_t* Ab = A + (size_t)b * sA;
  const bf16_t* Bb = Bt + (size_t)b * sB;

  // Staging: tile = 128 rows x 64 bf16 = 1024 16B-chunks; 4 insts x 256 threads.
  // XOR-swizzle: LDS chunk (r, kc) holds global chunk (r, kc ^ (r&7)) so that the
  // frag ds_read_b128 pattern (16 lanes reading 16 rows at one k-chunk) spreads
  // over all 32 banks (2-way only => free per m136).
  size_t aSrc[4], bSrc[4];
#pragma unroll
  for (int i = 0; i < 4; ++i) {
    int c = i * 256 + t;
    int r = c >> 3;
    int kcs = (c & 7) ^ (r & 7);
    aSrc[i] = (size_t)(m0 + r) * K + (size_t)kcs * 8;
    bSrc[i] = (size_t)(n0 + r) * K + (size_t)kcs * 8;
  }

  f32x4 acc[4][4];
#pragma unroll
  for (int mi = 0; mi < 4; ++mi)
#pragma unroll
    for (int ni = 0; ni < 4; ++ni)
      acc[mi][ni] = f32x4{0.f, 0.f, 0.f, 0.f};

  const int aRowB = (wm * 64 + l15) * (BK * 2);   // byte offset of this lane's A row
  const int bRowB = (wn * 64 + l15) * (BK * 2);
  const int xc0 = (quad ^ (lane & 7)) * 16;       // swizzled k-chunk byte offset, ks=0

  for (int k0 = 0; k0 < K; k0 += BK) {
#pragma unroll
    for (int i = 0; i < 4; ++i) {
      stage16(Ab + aSrc[i] + k0, ldsA + (i * 256 + t) * 16);
      stage16(Bb + bSrc[i] + k0, ldsB + (i * 256 + t) * 16);
    }
    __syncthreads();  // compiler emits vmcnt(0) drain before barrier

#pragma unroll
    for (int ks = 0; ks < 2; ++ks) {            // two K=32 MFMA steps per BK=64
      const int xo = xc0 ^ (ks * 64);           // (quad+4)^x == (quad^x)^4 for quad<4
      bf16x8 af[4], bfr[4];
#pragma unroll
      for (int mi = 0; mi < 4; ++mi)
        af[mi] = *(const bf16x8*)(ldsA + aRowB + mi * 2048 + xo);
#pragma unroll
      for (int ni = 0; ni < 4; ++ni)
        bfr[ni] = *(const bf16x8*)(ldsB + bRowB + ni * 2048 + xo);
#pragma unroll
      for (int mi = 0; mi < 4; ++mi)
#pragma unroll
        for (int ni = 0; ni < 4; ++ni)
          acc[mi][ni] = __builtin_amdgcn_mfma_f32_16x16x32_bf16(
              af[mi], bfr[ni], acc[mi][ni], 0, 0, 0);
    }
    __syncthreads();
  }

  // Epilogue. C/D layout (verified m89/m91): col = lane&15, row = quad*4 + reg.
  const int mBase = m0 + wm * 64 + quad * 4;
  const int nBase = n0 + wn * 64 + l15;

  if (OUT_MODE == 1) {
    bf16_t* Ct = (bf16_t*)Cv + (size_t)b * sC;
#pragma unroll
    for (int ni = 0; ni < 4; ++ni) {
      size_t colOff = (size_t)(nBase + ni * 16) * (size_t)M;
#pragma unroll
      for (int mi = 0; mi < 4; ++mi) {
        int rr = mBase + mi * 16;
        float v0 = acc[mi][ni][0], v1 = acc[mi][ni][1];
        float v2 = acc[mi][ni][2], v3 = acc[mi][ni][3];
        if (RELU) {
          v0 = fmaxf(v0, 0.f); v1 = fmaxf(v1, 0.f);
          v2 = fmaxf(v2, 0.f); v3 = fmaxf(v3, 0.f);
        }
        uint2 pkv;
        pkv.x = pk2(v0, v1);
        pkv.y = pk2(v2, v3);
        *(uint2*)(Ct + colOff + rr) = pkv;   // 4 consecutive rows of C^T -> 8B store
      }
    }
  } else if (OUT_MODE == 0) {
    bf16_t* C = (bf16_t*)Cv + (size_t)b * sC;
#pragma unroll
    for (int mi = 0; mi < 4; ++mi) {
#pragma unroll
      for (int j = 0; j < 4; ++j) {
        size_t rowOff = (size_t)(mBase + mi * 16 + j) * (size_t)N;
#pragma unroll
        for (int ni = 0; ni < 4; ++ni) {
          float v = acc[mi][ni][j];
          if (RELU) v = fmaxf(v, 0.f);
          C[rowOff + nBase + ni * 16] = __float2bfloat16(v);
        }
      }
    }
  } else {
    float* C = (float*)Cv + (size_t)b * sC;
#pragma unroll
    for (int mi = 0; mi < 4; ++mi) {
#pragma unroll
      for (int j = 0; j < 4; ++j) {
        size_t rowOff = (size_t)(mBase + mi * 16 + j) * (size_t)N;
#pragma unroll
        for (int ni = 0; ni < 4; ++ni) {
          float v = acc[mi][ni][j];
          if (RELU) v = fmaxf(v, 0.f);
          C[rowOff + nBase + ni * 16] = v;
        }
      }
    }
  }
}

// o = bf16(a * s), 4 elems/thread
__global__ void mul_cast_kernel(const float* __restrict__ a, const float* __restrict__ s,
                                bf16_t* __restrict__ o, int n4) {
  int i = blockIdx.x * blockDim.x + threadIdx.x;
  if (i < n4) {
    float4 av = ((const float4*)a)[i];
    float4 sv = ((const float4*)s)[i];
    uint2 r;
    r.x = pk2(av.x * sv.x, av.y * sv.y);
    r.y = pk2(av.z * sv.z, av.w * sv.w);
    ((uint2*)o)[i] = r;
  }
}

__global__ void cast_kernel(const float* __restrict__ a, bf16_t* __restrict__ o, int n4) {
  int i = blockIdx.x * blockDim.x + threadIdx.x;
  if (i < n4) {
    float4 av = ((const float4*)a)[i];
    uint2 r;
    r.x = pk2(av.x, av.y);
    r.y = pk2(av.z, av.w);
    ((uint2*)o)[i] = r;
  }
}

// wt[h*K + k] = bf16(w[k*H + h])   (w: [K,H] row-major -> wt: [H,K] row-major)
__global__ void transpose_cast_kernel(const float* __restrict__ w, bf16_t* __restrict__ wt,
                                      int K, int H) {
  int idx = blockIdx.x * blockDim.x + threadIdx.x;
  if (idx < K * H) {
    int h = idx / K;
    int k = idx - h * K;
    wt[idx] = __float2bfloat16(w[(size_t)k * H + h]);
  }
}

extern "C" void kernel_launch(void* const* d_in, const int* in_sizes, int n_in,
                              void* d_out, int out_size, void* d_ws, size_t ws_size,
                              hipStream_t stream) {
  const float* x   = (const float*)d_in[0];  // [4, 4096, 256]
  const float* adj = (const float*)d_in[1];  // [4096, 4096]
  const float* S   = (const float*)d_in[2];  // [4096, 4096]
  const float* W1  = (const float*)d_in[3];  // [256, 512]
  const float* W2  = (const float*)d_in[4];  // [512, 1024]
  const float* W3  = (const float*)d_in[5];  // [1024, 256]

  const int N = 4096, F = 256, H1 = 512, H2 = 1024, NC = 256, B = 4;

  // workspace layout (all sizes multiples of 4KB; total ~122 MB)
  char* ws = (char*)d_ws;
  bf16_t* AW  = (bf16_t*)ws; ws += (size_t)N * N * 2;       // 33.5 MB  bf16(adj*S)
  bf16_t* XB  = (bf16_t*)ws; ws += (size_t)B * N * F * 2;   //  8.4 MB  bf16(x)
  bf16_t* W1T = (bf16_t*)ws; ws += (size_t)F * H1 * 2;      // [512,256]
  bf16_t* W2T = (bf16_t*)ws; ws += (size_t)H1 * H2 * 2;     // [1024,512]
  bf16_t* W3T = (bf16_t*)ws; ws += (size_t)H2 * NC * 2;     // [256,1024]
  bf16_t* ST  = (bf16_t*)ws; ws += (size_t)B * H2 * N * 2;  // 33.5 MB  support^T (max H)
  bf16_t* HA  = (bf16_t*)ws; ws += (size_t)B * N * H1 * 2;  // 16.8 MB  h1
  bf16_t* HB  = (bf16_t*)ws; ws += (size_t)B * N * H2 * 2;  // 33.5 MB  h2

  // prep
  mul_cast_kernel<<<(N * N / 4 + 255) / 256, 256, 0, stream>>>(adj, S, AW, N * N / 4);
  cast_kernel<<<(B * N * F / 4 + 255) / 256, 256, 0, stream>>>(x, XB, B * N * F / 4);
  transpose_cast_kernel<<<(F * H1 + 255) / 256, 256, 0, stream>>>(W1, W1T, F, H1);
  transpose_cast_kernel<<<(H1 * H2 + 255) / 256, 256, 0, stream>>>(W2, W2T, H1, H2);
  transpose_cast_kernel<<<(H2 * NC + 255) / 256, 256, 0, stream>>>(W3, W3T, H2, NC);

  dim3 blk(THREADS);

  // layer 1: st1^T[H1,N] = (XB @ W1)^T ; h1 = relu(AW @ st1)
  gemm_bt<1, false><<<dim3(N / BM, H1 / BN, B), blk, 0, stream>>>(
      XB, W1T, ST, N, H1, F, (long)N * F, 0, (long)H1 * N);
  gemm_bt<0, true><<<dim3(N / BM, H1 / BN, B), blk, 0, stream>>>(
      AW, ST, HA, N, H1, N, 0, (long)H1 * N, (long)N * H1);

  // layer 2: st2^T[H2,N] = (h1 @ W2)^T ; h2 = relu(AW @ st2)
  gemm_bt<1, false><<<dim3(N / BM, H2 / BN, B), blk, 0, stream>>>(
      HA, W2T, ST, N, H2, H1, (long)N * H1, 0, (long)H2 * N);
  gemm_bt<0, true><<<dim3(N / BM, H2 / BN, B), blk, 0, stream>>>(
      AW, ST, HB, N, H2, N, 0, (long)H2 * N, (long)N * H2);

  // layer 3: st3^T[NC,N] = (h2 @ W3)^T ; out = AW @ st3 (fp32)
  gemm_bt<1, false><<<dim3(N / BM, NC / BN, B), blk, 0, stream>>>(
      HB, W3T, ST, N, NC, H2, (long)N * H2, 0, (long)NC * N);
  gemm_bt<2, false><<<dim3(N / BM, NC / BN, B), blk, 0, stream>>>(
      AW, ST, d_out, N, NC, N, 0, (long)NC * N, (long)N * NC);
}

// Round 3
// 467.424 us; speedup vs baseline: 1.0715x; 1.0715x over previous
//
#include <hip/hip_runtime.h>
#include <hip/hip_bf16.h>
#include <stdint.h>
#include <stddef.h>

typedef __bf16 bf16x8 __attribute__((ext_vector_type(8)));
typedef float f32x4 __attribute__((ext_vector_type(4)));
typedef __hip_bfloat16 bf16_t;

#define BM 128
#define BN 128
#define BK 64
#define THREADS 256

// async global->LDS, 16B per lane. LDS dest must be wave-uniform-base + lane*16.
__device__ __forceinline__ void stage16(const void* g, void* l) {
  __builtin_amdgcn_global_load_lds(
      (const __attribute__((address_space(1))) uint32_t*)g,
      (__attribute__((address_space(3))) uint32_t*)l, 16, 0, 0);
}

__device__ __forceinline__ unsigned pk2(float x, float y) {
  bf16_t a = __float2bfloat16(x);
  bf16_t b = __float2bfloat16(y);
  unsigned short ua = *(unsigned short*)&a;
  unsigned short ub = *(unsigned short*)&b;
  return (unsigned)ua | ((unsigned)ub << 16);
}

// C = A @ Bt^T.  A: [M,K] row-major bf16.  Bt: [N,K] row-major bf16.
// OUT_MODE 0: C bf16 row-major [M,N] (ld=N)
// OUT_MODE 1: C bf16 TRANSPOSED [N,M] (ld=M)  (for support^T buffers)
// OUT_MODE 2: C f32 row-major [M,N]
// sA/sB/sC: per-batch element strides (blockIdx.z = batch).
// R1-verified core: 16x16x32 MFMA, row-major LDS with per-row XOR chunk
// swizzle (SQ_LDS_BANK_CONFLICT == 0 measured), coalesced 8-lanes-per-row
// global_load_lds staging. Do not modify without a full re-verify.
template <int OUT_MODE, bool RELU>
__global__ void gemm_bt(const bf16_t* __restrict__ A, const bf16_t* __restrict__ Bt,
                        void* __restrict__ Cv, int M, int N, int K,
                        long sA, long sB, long sC) {
  __shared__ __align__(16) char lds[(BM + BN) * BK * 2];  // 32 KB
  char* ldsA = lds;
  char* ldsB = lds + BM * BK * 2;

  const int t = threadIdx.x;
  const int lane = t & 63;
  const int w = t >> 6;
  const int wm = w >> 1, wn = w & 1;          // 2x2 wave grid, each wave 64x64
  const int quad = lane >> 4, l15 = lane & 15;
  const int m0 = blockIdx.x * BM;
  const int n0 = blockIdx.y * BN;
  const int b = blockIdx.z;

  const bf16_t* Ab = A + (size_t)b * sA;
  const bf16_t* Bb = Bt + (size_t)b * sB;

  // Staging: tile = 128 rows x 64 bf16 = 1024 16B-chunks; 4 insts x 256 threads.
  // XOR-swizzle: LDS chunk (r, kc) holds global chunk (r, kc ^ (r&7)) so that the
  // frag ds_read_b128 pattern (16 lanes reading 16 rows at one k-chunk) spreads
  // over all 32 banks (2-way only => free per m136).
  size_t aSrc[4], bSrc[4];
#pragma unroll
  for (int i = 0; i < 4; ++i) {
    int c = i * 256 + t;
    int r = c >> 3;
    int kcs = (c & 7) ^ (r & 7);
    aSrc[i] = (size_t)(m0 + r) * K + (size_t)kcs * 8;
    bSrc[i] = (size_t)(n0 + r) * K + (size_t)kcs * 8;
  }

  f32x4 acc[4][4];
#pragma unroll
  for (int mi = 0; mi < 4; ++mi)
#pragma unroll
    for (int ni = 0; ni < 4; ++ni)
      acc[mi][ni] = f32x4{0.f, 0.f, 0.f, 0.f};

  const int aRowB = (wm * 64 + l15) * (BK * 2);   // byte offset of this lane's A row
  const int bRowB = (wn * 64 + l15) * (BK * 2);
  const int xc0 = (quad ^ (lane & 7)) * 16;       // swizzled k-chunk byte offset, ks=0

  for (int k0 = 0; k0 < K; k0 += BK) {
#pragma unroll
    for (int i = 0; i < 4; ++i) {
      stage16(Ab + aSrc[i] + k0, ldsA + (i * 256 + t) * 16);
      stage16(Bb + bSrc[i] + k0, ldsB + (i * 256 + t) * 16);
    }
    __syncthreads();  // compiler emits vmcnt(0) drain before barrier

#pragma unroll
    for (int ks = 0; ks < 2; ++ks) {            // two K=32 MFMA steps per BK=64
      const int xo = xc0 ^ (ks * 64);           // (quad+4)^x == (quad^x)^4 for quad<4
      bf16x8 af[4], bfr[4];
#pragma unroll
      for (int mi = 0; mi < 4; ++mi)
        af[mi] = *(const bf16x8*)(ldsA + aRowB + mi * 2048 + xo);
#pragma unroll
      for (int ni = 0; ni < 4; ++ni)
        bfr[ni] = *(const bf16x8*)(ldsB + bRowB + ni * 2048 + xo);
#pragma unroll
      for (int mi = 0; mi < 4; ++mi)
#pragma unroll
        for (int ni = 0; ni < 4; ++ni)
          acc[mi][ni] = __builtin_amdgcn_mfma_f32_16x16x32_bf16(
              af[mi], bfr[ni], acc[mi][ni], 0, 0, 0);
    }
    __syncthreads();
  }

  // Epilogue. C/D layout (verified m89/m91): col = lane&15, row = quad*4 + reg.
  const int mBase = m0 + wm * 64 + quad * 4;
  const int nBase = n0 + wn * 64 + l15;

  if (OUT_MODE == 1) {
    bf16_t* Ct = (bf16_t*)Cv + (size_t)b * sC;
#pragma unroll
    for (int ni = 0; ni < 4; ++ni) {
      size_t colOff = (size_t)(nBase + ni * 16) * (size_t)M;
#pragma unroll
      for (int mi = 0; mi < 4; ++mi) {
        int rr = mBase + mi * 16;
        float v0 = acc[mi][ni][0], v1 = acc[mi][ni][1];
        float v2 = acc[mi][ni][2], v3 = acc[mi][ni][3];
        if (RELU) {
          v0 = fmaxf(v0, 0.f); v1 = fmaxf(v1, 0.f);
          v2 = fmaxf(v2, 0.f); v3 = fmaxf(v3, 0.f);
        }
        uint2 pkv;
        pkv.x = pk2(v0, v1);
        pkv.y = pk2(v2, v3);
        *(uint2*)(Ct + colOff + rr) = pkv;   // 4 consecutive rows of C^T -> 8B store
      }
    }
  } else if (OUT_MODE == 0) {
    bf16_t* C = (bf16_t*)Cv + (size_t)b * sC;
#pragma unroll
    for (int mi = 0; mi < 4; ++mi) {
#pragma unroll
      for (int j = 0; j < 4; ++j) {
        size_t rowOff = (size_t)(mBase + mi * 16 + j) * (size_t)N;
#pragma unroll
        for (int ni = 0; ni < 4; ++ni) {
          float v = acc[mi][ni][j];
          if (RELU) v = fmaxf(v, 0.f);
          C[rowOff + nBase + ni * 16] = __float2bfloat16(v);
        }
      }
    }
  } else {
    float* C = (float*)Cv + (size_t)b * sC;
#pragma unroll
    for (int mi = 0; mi < 4; ++mi) {
#pragma unroll
      for (int j = 0; j < 4; ++j) {
        size_t rowOff = (size_t)(mBase + mi * 16 + j) * (size_t)N;
#pragma unroll
        for (int ni = 0; ni < 4; ++ni) {
          float v = acc[mi][ni][j];
          if (RELU) v = fmaxf(v, 0.f);
          C[rowOff + nBase + ni * 16] = v;
        }
      }
    }
  }
}

// o = bf16(a * s), 4 elems/thread
__global__ void mul_cast_kernel(const float* __restrict__ a, const float* __restrict__ s,
                                bf16_t* __restrict__ o, int n4) {
  int i = blockIdx.x * blockDim.x + threadIdx.x;
  if (i < n4) {
    float4 av = ((const float4*)a)[i];
    float4 sv = ((const float4*)s)[i];
    uint2 r;
    r.x = pk2(av.x * sv.x, av.y * sv.y);
    r.y = pk2(av.z * sv.z, av.w * sv.w);
    ((uint2*)o)[i] = r;
  }
}

__global__ void cast_kernel(const float* __restrict__ a, bf16_t* __restrict__ o, int n4) {
  int i = blockIdx.x * blockDim.x + threadIdx.x;
  if (i < n4) {
    float4 av = ((const float4*)a)[i];
    uint2 r;
    r.x = pk2(av.x, av.y);
    r.y = pk2(av.z, av.w);
    ((uint2*)o)[i] = r;
  }
}

// All three weight transposes in one launch.
// wt[h*K + k] = bf16(w[k*H + h]); ranges laid out flat.
__global__ void transpose_cast3_kernel(const float* __restrict__ W1, const float* __restrict__ W2,
                                       const float* __restrict__ W3, bf16_t* __restrict__ W1T,
                                       bf16_t* __restrict__ W2T, bf16_t* __restrict__ W3T) {
  const int n1 = 256 * 512;          // W1
  const int n2 = 512 * 1024;         // W2
  const int n3 = 1024 * 256;         // W3
  int idx = blockIdx.x * blockDim.x + threadIdx.x;
  if (idx < n1) {
    int K = 256, H = 512;
    int h = idx / K, k = idx - h * K;
    W1T[idx] = __float2bfloat16(W1[(size_t)k * H + h]);
  } else if (idx < n1 + n2) {
    int i = idx - n1;
    int K = 512, H = 1024;
    int h = i / K, k = i - h * K;
    W2T[i] = __float2bfloat16(W2[(size_t)k * H + h]);
  } else if (idx < n1 + n2 + n3) {
    int i = idx - n1 - n2;
    int K = 1024, H = 256;
    int h = i / K, k = i - h * K;
    W3T[i] = __float2bfloat16(W3[(size_t)k * H + h]);
  }
}

extern "C" void kernel_launch(void* const* d_in, const int* in_sizes, int n_in,
                              void* d_out, int out_size, void* d_ws, size_t ws_size,
                              hipStream_t stream) {
  const float* x   = (const float*)d_in[0];  // [4, 4096, 256]
  const float* adj = (const float*)d_in[1];  // [4096, 4096]
  const float* S   = (const float*)d_in[2];  // [4096, 4096]
  const float* W1  = (const float*)d_in[3];  // [256, 512]
  const float* W2  = (const float*)d_in[4];  // [512, 1024]
  const float* W3  = (const float*)d_in[5];  // [1024, 256]

  const int N = 4096, F = 256, H1 = 512, H2 = 1024, NC = 256, B = 4;

  // Compact ping-pong workspace: 3x 33.5 MB + 1.84 MB weights = 97.8 MiB
  // (was 121.8 MiB in R1/R2 — shrunk to reduce OOB exposure, prime suspect
  // for R2's post-timing divergence).
  // Liveness: P2 holds XB until gemm1's last read, then HA, then HB.
  //           P1 holds ST for each layer (max 4*1024*4096 bf16 = 33.5 MB).
  char* ws = (char*)d_ws;
  bf16_t* AW  = (bf16_t*)ws; ws += (size_t)N * N * 2;       // bf16(adj*S)
  bf16_t* P1  = (bf16_t*)ws; ws += (size_t)B * H2 * N * 2;  // support^T buffers
  bf16_t* P2  = (bf16_t*)ws; ws += (size_t)B * N * H2 * 2;  // XB -> h1 -> h2
  bf16_t* W1T = (bf16_t*)ws; ws += (size_t)F * H1 * 2;      // [512,256]
  bf16_t* W2T = (bf16_t*)ws; ws += (size_t)H1 * H2 * 2;     // [1024,512]
  bf16_t* W3T = (bf16_t*)ws; ws += (size_t)H2 * NC * 2;     // [256,1024]

  bf16_t* XB = P2;  // x cast to bf16, dead after gemm1

  // prep
  mul_cast_kernel<<<(N * N / 4 + 255) / 256, 256, 0, stream>>>(adj, S, AW, N * N / 4);
  cast_kernel<<<(B * N * F / 4 + 255) / 256, 256, 0, stream>>>(x, XB, B * N * F / 4);
  {
    int total = 256 * 512 + 512 * 1024 + 1024 * 256;
    transpose_cast3_kernel<<<(total + 255) / 256, 256, 0, stream>>>(W1, W2, W3, W1T, W2T, W3T);
  }

  dim3 blk(THREADS);

  // layer 1: st1^T[H1,N] = (XB @ W1)^T -> P1 ; h1 = relu(AW @ st1) -> P2
  gemm_bt<1, false><<<dim3(N / BM, H1 / BN, B), blk, 0, stream>>>(
      XB, W1T, P1, N, H1, F, (long)N * F, 0, (long)H1 * N);
  gemm_bt<0, true><<<dim3(N / BM, H1 / BN, B), blk, 0, stream>>>(
      AW, P1, P2, N, H1, N, 0, (long)H1 * N, (long)N * H1);

  // layer 2: st2^T[H2,N] = (h1 @ W2)^T -> P1 ; h2 = relu(AW @ st2) -> P2
  gemm_bt<1, false><<<dim3(N / BM, H2 / BN, B), blk, 0, stream>>>(
      P2, W2T, P1, N, H2, H1, (long)N * H1, 0, (long)H2 * N);
  gemm_bt<0, true><<<dim3(N / BM, H2 / BN, B), blk, 0, stream>>>(
      AW, P1, P2, N, H2, N, 0, (long)H2 * N, (long)N * H2);

  // layer 3: st3^T[NC,N] = (h2 @ W3)^T -> P1 ; out = AW @ st3 (fp32) -> d_out
  gemm_bt<1, false><<<dim3(N / BM, NC / BN, B), blk, 0, stream>>>(
      P2, W3T, P1, N, NC, H2, (long)N * H2, 0, (long)NC * N);
  gemm_bt<2, false><<<dim3(N / BM, NC / BN, B), blk, 0, stream>>>(
      AW, P1, d_out, N, NC, N, 0, (long)NC * N, (long)N * NC);
}